// Round 1
// baseline (598.566 us; speedup 1.0000x reference)
//
#include <hip/hip_runtime.h>
#include <hip/hip_bf16.h>

// Soft-DTW gradient (batch=64, m=n=256, gamma=0.01).
// Forward: V[i][j] = theta[i-1][j-1] + softmin_g(V[i][j-1], V[i-1][j-1], V[i-1][j])
//   A(i,j) := softmin value = V - theta  (stored to ws, diag-major, fp32)
// Backward: E[i][j] = sum over successors s in {(i,j+1),(i+1,j+1),(i+1,j)}:
//   exp((A(s) - V[i][j])/g) * E[s]   ; E(m,n)=1 seed (Q[m+1][n+1]=1 corner).
// Exponent <= 0 always (A(s) is softmin over a set containing V[i][j]).

#define MM 256
#define NN 256
#define NDIAG 513          // diagonals d = 0..512
#define DSTR 257           // diag stride (index i = 0..256)
#define BIGV 1.0e10f
#define GAMMA 0.01f
#define INVG 100.0f

__global__ __launch_bounds__(256) void dtw_grad_kernel(
    const float* __restrict__ D,   // [B][256][256]
    float* __restrict__ out,       // [256][256], pre-zeroed
    float* __restrict__ ws,        // [B][NDIAG][DSTR]
    float inv_batch)
{
    const int b = blockIdx.x;
    const int t = threadIdx.x;            // 0..255
    const int i = t + 1;                  // row 1..256
    const float* __restrict__ th = D + (size_t)b * (MM * NN);
    float* __restrict__ gA = ws + (size_t)b * (NDIAG * DSTR);

    __shared__ float V[4][258];

    // ---- forward DP over anti-diagonals ----
    if (t == 0) {
        V[0][0] = 0.0f;      // cell (0,0), diag 0
        V[1][0] = BIGV;      // cell (0,1), diag 1
        V[1][1] = BIGV;      // cell (1,0), diag 1
    }
    __syncthreads();

    for (int d = 2; d <= MM + NN; ++d) {
        float* cur       = V[d & 3];
        const float* m1  = V[(d - 1) & 3];
        const float* m2  = V[(d - 2) & 3];
        const int j = d - i;
        if (j >= 1 && j <= NN) {
            const float vl = m1[i];       // V(i,   j-1)  diag d-1
            const float vu = m1[i - 1];   // V(i-1, j  )  diag d-1
            const float vd = m2[i - 1];   // V(i-1, j-1)  diag d-2
            const float mn = fminf(vl, fminf(vu, vd));
            const float s = __expf((mn - vl) * INVG)
                          + __expf((mn - vd) * INVG)
                          + __expf((mn - vu) * INVG);
            const float a = mn - GAMMA * __logf(s);     // softmin value A(i,j)
            cur[i] = a + th[(i - 1) * NN + (j - 1)];    // V(i,j)
            gA[d * DSTR + i] = a;
        } else if (j == 0) {
            cur[i] = BIGV;                // cell (i, 0)
        }
        if (t == 0 && d <= NN) cur[0] = BIGV;  // cell (0, d)
        __syncthreads();
    }

    // ---- backward E recursion over anti-diagonals (d = 512 .. 2) ----
    __shared__ float E[4][258];
    __shared__ float A[4][258];
    for (int k = t; k < 4 * 258; k += 256) {
        (&E[0][0])[k] = 0.0f;
        (&A[0][0])[k] = 0.0f;
    }
    __syncthreads();

    for (int d = MM + NN; d >= 2; --d) {
        float* eCur      = E[d & 3];
        const float* e1  = E[(d + 1) & 3];   // diag d+1
        const float* e2  = E[(d + 2) & 3];   // diag d+2
        float* aCur      = A[d & 3];
        const float* a1  = A[(d + 1) & 3];
        const float* a2  = A[(d + 2) & 3];
        const int j = d - i;
        float e = 0.0f;
        const bool valid = (j >= 1 && j <= NN);
        if (valid) {
            const float aown = gA[d * DSTR + i];                 // A(i,j), coalesced
            const float Vown = aown + th[(i - 1) * NN + (j - 1)];
            if (j + 1 <= NN)
                e += __expf((a1[i] - Vown) * INVG) * e1[i];          // (i,   j+1)
            if (i + 1 <= MM && j + 1 <= NN)
                e += __expf((a2[i + 1] - Vown) * INVG) * e2[i + 1];  // (i+1, j+1)
            if (i + 1 <= MM)
                e += __expf((a1[i + 1] - Vown) * INVG) * e1[i + 1];  // (i+1, j  )
            if (i == MM && j == NN) e = 1.0f;                        // corner seed
            aCur[i] = aown;
            atomicAdd(out + (i - 1) * NN + (j - 1), e * inv_batch);
        }
        eCur[t + 1] = valid ? e : 0.0f;
        __syncthreads();
    }
}

extern "C" void kernel_launch(void* const* d_in, const int* in_sizes, int n_in,
                              void* d_out, int out_size, void* d_ws, size_t ws_size,
                              hipStream_t stream) {
    const float* D = (const float*)d_in[0];
    float* out = (float*)d_out;
    float* ws = (float*)d_ws;
    const int B = in_sizes[0] / (MM * NN);   // 64

    hipMemsetAsync(d_out, 0, (size_t)out_size * sizeof(float), stream);
    dtw_grad_kernel<<<dim3(B), dim3(256), 0, stream>>>(D, out, ws, 1.0f / (float)B);
}